// Round 3
// baseline (279.428 us; speedup 1.0000x reference)
//
#include <hip/hip_runtime.h>

#define CC 1024
#define TT 1024
#define SEG 16                      // TT / 64 lanes
#define NROWS 16384                 // B*C
#define NTOT ((size_t)NROWS * TT)

typedef float f32x4 __attribute__((ext_vector_type(4)));

__global__ __launch_bounds__(256, 8) void snn_fused_kernel(
    const float* __restrict__ current,
    const float* __restrict__ beta,
    const float* __restrict__ v_init,
    const float* __restrict__ v_th,
    float* __restrict__ out)
{
    const int tid  = blockIdx.x * blockDim.x + threadIdx.x;
    const int row  = tid >> 6;          // one wave64 per (b,c) row
    const int lane = threadIdx.x & 63;

    const float bet = beta[row & (CC - 1)];
    const size_t base = (size_t)row * TT + (size_t)(lane * SEG);

    // ---- prefetch BOTH input streams up front (8 independent dwordx4) ----
    const f32x4* cp = reinterpret_cast<const f32x4*>(current + base);
    const f32x4* vp = reinterpret_cast<const f32x4*>(v_th + base);
    f32x4 c4[4], t4[4];
#pragma unroll
    for (int q = 0; q < 4; ++q) c4[q] = cp[q];
#pragma unroll
    for (int q = 0; q < 4; ++q) t4[q] = vp[q];

    float cur[SEG];
#pragma unroll
    for (int q = 0; q < 4; ++q) {
        cur[q*4+0] = c4[q].x; cur[q*4+1] = c4[q].y;
        cur[q*4+2] = c4[q].z; cur[q*4+3] = c4[q].w;
    }
    if (lane == 0) cur[0] = fmaf(bet, v_init[row], cur[0]);

    // ---- local recurrence (unseeded) -> segment transform (beta^16, m) ----
    float m = 0.f;
#pragma unroll
    for (int j = 0; j < SEG; ++j) m = fmaf(bet, m, cur[j]);

    float b2 = bet * bet, b4 = b2 * b2, b8 = b4 * b4;
    float aa = b8 * b8;   // a = beta^16
    float bb = m;

    // ---- cross-lane inclusive affine scan ----
#pragma unroll
    for (int d = 1; d < 64; d <<= 1) {
        float ap = __shfl_up(aa, d);
        float bp = __shfl_up(bb, d);
        if (lane >= d) { bb = fmaf(aa, bp, bb); aa *= ap; }
    }
    float carry = __shfl_up(bb, 1);
    if (lane == 0) carry = 0.f;

    // ---- replay seeded; spikes inline; cur[] := membrane ----
    float vth_[SEG];
#pragma unroll
    for (int q = 0; q < 4; ++q) {
        vth_[q*4+0] = t4[q].x; vth_[q*4+1] = t4[q].y;
        vth_[q*4+2] = t4[q].z; vth_[q*4+3] = t4[q].w;
    }
    int mask = 0, s1 = 0, s2 = 0;
    m = carry;
#pragma unroll
    for (int j = 0; j < SEG; ++j) {
        m = fmaf(bet, m, cur[j]);
        cur[j] = m;
        const int s = (m - vth_[j] > 0.f) ? 1 : 0;
        mask |= s << j;
        s1 += s; s2 += s1;
    }

    // ---- store membrane immediately (frees cur/vth registers) ----
    f32x4* o2 = reinterpret_cast<f32x4*>(out + 2 * NTOT + base);
#pragma unroll
    for (int q = 0; q < 4; ++q) {
        f32x4 v = { cur[q*4+0], cur[q*4+1], cur[q*4+2], cur[q*4+3] };
        __builtin_nontemporal_store(v, &o2[q]);
    }

    // ---- ONE fused scan for both prefix quantities:
    //   S1 = segment spike count;  W(range) = sum over range of (16*P1_in_range + s2)
    //   combine (prev ∘ self): W = Wp + Ws + 16*d*S1p   (self window = d lanes)
    int S1 = s1, W = s2;
#pragma unroll
    for (int d = 1; d < 64; d <<= 1) {
        const int Sp = __shfl_up(S1, d);
        const int Wp = __shfl_up(W, d);
        if (lane >= d) { W = Wp + W + (SEG * d) * Sp; S1 = Sp + S1; }
    }
    int P1 = __shfl_up(S1, 1);
    int PZ = __shfl_up(W, 1);
    if (lane == 0) { P1 = 0; PZ = 0; }

    // ---- finalize z, out; recompute local cumsums from the spike mask ----
    f32x4* o0 = reinterpret_cast<f32x4*>(out + base);
    f32x4* o1 = reinterpret_cast<f32x4*>(out + NTOT + base);
    s1 = 0; s2 = 0;
#pragma unroll
    for (int q = 0; q < 4; ++q) {
        float zf[4], of[4];
#pragma unroll
        for (int r = 0; r < 4; ++r) {
            const int j = q * 4 + r;
            const int s = (mask >> j) & 1;
            s1 += s; s2 += s1;
            const int z = PZ + (j + 1) * P1 + s2;
            zf[r] = (float)z;
            of[r] = (z == 1) ? 1.0f : 0.0f;
        }
        f32x4 ov = { of[0], of[1], of[2], of[3] };
        f32x4 zv = { zf[0], zf[1], zf[2], zf[3] };
        __builtin_nontemporal_store(ov, &o0[q]);
        __builtin_nontemporal_store(zv, &o1[q]);
    }
}

extern "C" void kernel_launch(void* const* d_in, const int* in_sizes, int n_in,
                              void* d_out, int out_size, void* d_ws, size_t ws_size,
                              hipStream_t stream) {
    const float* current = (const float*)d_in[0];
    const float* beta    = (const float*)d_in[1];
    const float* v_init  = (const float*)d_in[2];
    const float* v_th    = (const float*)d_in[3];
    float* outp = (float*)d_out;

    const int threads = 256;                         // 4 waves/block
    const int blocks  = (NROWS * 64) / threads;      // 4096, exact
    snn_fused_kernel<<<blocks, threads, 0, stream>>>(current, beta, v_init, v_th, outp);
}